// Round 1
// baseline (547.474 us; speedup 1.0000x reference)
//
#include <hip/hip_runtime.h>

#define N_NODES 200000
#define DIM 480            // 120 float4 per row
#define N_SEG 4096
#define VEC (DIM / 4)      // 120

// 1) histogram of labels into counts[N_SEG]
__global__ void hist_kernel(const int* __restrict__ labels,
                            int* __restrict__ counts, int n) {
    int i = blockIdx.x * blockDim.x + threadIdx.x;
    if (i < n) atomicAdd(&counts[labels[i]], 1);
}

// 2) exclusive scan of counts[4096] -> cursor[4096]; 1 block, 256 thr x 16 elems
__global__ void scan_kernel(const int* __restrict__ counts,
                            int* __restrict__ cursor) {
    __shared__ int part[256];
    int t = threadIdx.x;
    int local[16];
    int base = t * 16;
    int sum = 0;
#pragma unroll
    for (int i = 0; i < 16; ++i) { local[i] = counts[base + i]; sum += local[i]; }
    part[t] = sum;
    __syncthreads();
    // Hillis-Steele inclusive scan over the 256 partial sums
    for (int off = 1; off < 256; off <<= 1) {
        int add = (t >= off) ? part[t - off] : 0;
        __syncthreads();
        part[t] += add;
        __syncthreads();
    }
    int excl = (t == 0) ? 0 : part[t - 1];
#pragma unroll
    for (int i = 0; i < 16; ++i) { cursor[base + i] = excl; excl += local[i]; }
}

// 3) counting-sort scatter: sorted_idx[pos] = node index
//    afterwards cursor[s] == segment end offset
__global__ void scatter_kernel(const int* __restrict__ labels,
                               int* __restrict__ cursor,
                               int* __restrict__ sorted_idx, int n) {
    int i = blockIdx.x * blockDim.x + threadIdx.x;
    if (i < n) {
        int pos = atomicAdd(&cursor[labels[i]], 1);
        sorted_idx[pos] = i;
    }
}

// 4) per-segment gather + mean. One block per segment; lanes 0..119 each own
//    one float4 column slice; each row read = 120 lanes x 16B = the exact
//    1920B contiguous row (coalesced, each input byte read once).
__global__ __launch_bounds__(128) void gather_mean_kernel(
    const float* __restrict__ x,
    const int* __restrict__ sorted_idx,
    const int* __restrict__ counts,
    const int* __restrict__ cursor,
    float* __restrict__ out) {
    int s = blockIdx.x;
    int cnt = counts[s];
    int end = cursor[s];
    int start = end - cnt;
    int t = threadIdx.x;
    if (t >= VEC) return;

    float4 acc = make_float4(0.f, 0.f, 0.f, 0.f);
#pragma unroll 2
    for (int j = start; j < end; ++j) {
        int node = sorted_idx[j];                     // wave-uniform -> s_load
        const float4* row = (const float4*)(x + (size_t)node * DIM);
        float4 v = row[t];
        acc.x += v.x; acc.y += v.y; acc.z += v.z; acc.w += v.w;
    }
    float inv = (cnt > 0) ? (1.0f / (float)cnt) : 0.0f;
    float4 r = make_float4(acc.x * inv, acc.y * inv, acc.z * inv, acc.w * inv);
    ((float4*)(out + (size_t)s * DIM))[t] = r;
}

extern "C" void kernel_launch(void* const* d_in, const int* in_sizes, int n_in,
                              void* d_out, int out_size, void* d_ws, size_t ws_size,
                              hipStream_t stream) {
    const float* x      = (const float*)d_in[0];
    const int*   labels = (const int*)d_in[1];
    float* out = (float*)d_out;

    // workspace layout: counts[4096] | cursor[4096] | sorted_idx[200000]
    int* counts     = (int*)d_ws;
    int* cursor     = counts + N_SEG;
    int* sorted_idx = cursor + N_SEG;

    hipMemsetAsync(counts, 0, N_SEG * sizeof(int), stream);

    hist_kernel<<<(N_NODES + 255) / 256, 256, 0, stream>>>(labels, counts, N_NODES);
    scan_kernel<<<1, 256, 0, stream>>>(counts, cursor);
    scatter_kernel<<<(N_NODES + 255) / 256, 256, 0, stream>>>(labels, cursor,
                                                              sorted_idx, N_NODES);
    gather_mean_kernel<<<N_SEG, 128, 0, stream>>>(x, sorted_idx, counts, cursor, out);
}

// Round 2
// 542.284 us; speedup vs baseline: 1.0096x; 1.0096x over previous
//
#include <hip/hip_runtime.h>

#define N_NODES 200000
#define DIM 480            // 120 float4 per row
#define N_SEG 4096
#define VEC (DIM / 4)      // 120
#define CHUNK 8            // rows in flight per wave

// 1) histogram of labels into counts[N_SEG]
__global__ void hist_kernel(const int* __restrict__ labels,
                            int* __restrict__ counts, int n) {
    int i = blockIdx.x * blockDim.x + threadIdx.x;
    if (i < n) atomicAdd(&counts[labels[i]], 1);
}

// 2) exclusive scan of counts[4096] -> cursor[4096]; 1 block, 256 thr x 16 elems
__global__ void scan_kernel(const int* __restrict__ counts,
                            int* __restrict__ cursor) {
    __shared__ int part[256];
    int t = threadIdx.x;
    int local[16];
    int base = t * 16;
    int sum = 0;
#pragma unroll
    for (int i = 0; i < 16; ++i) { local[i] = counts[base + i]; sum += local[i]; }
    part[t] = sum;
    __syncthreads();
    for (int off = 1; off < 256; off <<= 1) {
        int add = (t >= off) ? part[t - off] : 0;
        __syncthreads();
        part[t] += add;
        __syncthreads();
    }
    int excl = (t == 0) ? 0 : part[t - 1];
#pragma unroll
    for (int i = 0; i < 16; ++i) { cursor[base + i] = excl; excl += local[i]; }
}

// 3) counting-sort scatter: sorted_idx[pos] = node index
__global__ void scatter_kernel(const int* __restrict__ labels,
                               int* __restrict__ cursor,
                               int* __restrict__ sorted_idx, int n) {
    int i = blockIdx.x * blockDim.x + threadIdx.x;
    if (i < n) {
        int pos = atomicAdd(&cursor[labels[i]], 1);
        sorted_idx[pos] = i;
    }
}

// 4) per-segment gather + mean, 8 rows in flight per iteration.
//    Tail handled inside the 8-wide chunk with clamped index + 0/1 weight so
//    the dependent-load chain never serializes.
__global__ __launch_bounds__(128) void gather_mean_kernel(
    const float* __restrict__ x,
    const int* __restrict__ sorted_idx,
    const int* __restrict__ counts,
    const int* __restrict__ cursor,
    float* __restrict__ out) {
    int s = blockIdx.x;
    int cnt = counts[s];
    int end = cursor[s];
    int start = end - cnt;
    int t = threadIdx.x;
    if (t >= VEC) return;

    float4 acc = make_float4(0.f, 0.f, 0.f, 0.f);
    if (cnt > 0) {
        for (int j = start; j < end; j += CHUNK) {
            // 8 independent index loads (same addr across lanes -> broadcast,
            // hits L2); clamp keeps them valid, weight zeroes the overshoot.
            int   idx[CHUNK];
            float w[CHUNK];
#pragma unroll
            for (int k = 0; k < CHUNK; ++k) {
                int jj = j + k;
                w[k]   = (jj < end) ? 1.0f : 0.0f;
                idx[k] = sorted_idx[(jj < end) ? jj : start];
            }
            // 8 independent 16B row loads in flight
            float4 v[CHUNK];
#pragma unroll
            for (int k = 0; k < CHUNK; ++k) {
                const float4* row = (const float4*)(x + (size_t)idx[k] * DIM);
                v[k] = row[t];
            }
#pragma unroll
            for (int k = 0; k < CHUNK; ++k) {
                acc.x = fmaf(w[k], v[k].x, acc.x);
                acc.y = fmaf(w[k], v[k].y, acc.y);
                acc.z = fmaf(w[k], v[k].z, acc.z);
                acc.w = fmaf(w[k], v[k].w, acc.w);
            }
        }
    }
    float inv = (cnt > 0) ? (1.0f / (float)cnt) : 0.0f;
    float4 r = make_float4(acc.x * inv, acc.y * inv, acc.z * inv, acc.w * inv);
    ((float4*)(out + (size_t)s * DIM))[t] = r;
}

extern "C" void kernel_launch(void* const* d_in, const int* in_sizes, int n_in,
                              void* d_out, int out_size, void* d_ws, size_t ws_size,
                              hipStream_t stream) {
    const float* x      = (const float*)d_in[0];
    const int*   labels = (const int*)d_in[1];
    float* out = (float*)d_out;

    // workspace layout: counts[4096] | cursor[4096] | sorted_idx[200000]
    int* counts     = (int*)d_ws;
    int* cursor     = counts + N_SEG;
    int* sorted_idx = cursor + N_SEG;

    hipMemsetAsync(counts, 0, N_SEG * sizeof(int), stream);

    hist_kernel<<<(N_NODES + 255) / 256, 256, 0, stream>>>(labels, counts, N_NODES);
    scan_kernel<<<1, 256, 0, stream>>>(counts, cursor);
    scatter_kernel<<<(N_NODES + 255) / 256, 256, 0, stream>>>(labels, cursor,
                                                              sorted_idx, N_NODES);
    gather_mean_kernel<<<N_SEG, 128, 0, stream>>>(x, sorted_idx, counts, cursor, out);
}